// Round 6
// baseline (398.947 us; speedup 1.0000x reference)
//
#include <hip/hip_runtime.h>

#define NEQ_   4096
#define XDIM_  6144
#define EEDGES 32768

typedef __bf16 bf16x8 __attribute__((ext_vector_type(8)));
typedef float  f32x4  __attribute__((ext_vector_type(4)));

__device__ __forceinline__ unsigned short f2bf(float f) {
    union { float f; unsigned u; } v; v.f = f;
    unsigned r = v.u + 0x7FFFu + ((v.u >> 16) & 1u);   // RNE
    return (unsigned short)(r >> 16);
}

// pack two relu'd floats to bf16 pair (round-half-up; inputs are >= 0 post-relu)
__device__ __forceinline__ unsigned pk2(float x, float y) {
    x = fmaxf(x, 0.f); y = fmaxf(y, 0.f);
    union { float f; unsigned u; } ax, ay; ax.f = x; ay.f = y;
    return ((ax.u + 0x8000u) >> 16) | ((ay.u + 0x8000u) & 0xFFFF0000u);
}

__device__ __forceinline__ void gll16(const void* g, void* l) {
    __builtin_amdgcn_global_load_lds(
        (const __attribute__((address_space(1))) unsigned int*)g,
        (__attribute__((address_space(3))) unsigned int*)l, 16, 0, 0);
}

// device-scope grid barrier: all blocks must be co-resident (128 blocks on 256 CUs)
__device__ __forceinline__ void gridbar(int* c, int nblk) {
    __syncthreads();
    if (threadIdx.x == 0) {
        __threadfence();
        __hip_atomic_fetch_add(c, 1, __ATOMIC_ACQ_REL, __HIP_MEMORY_SCOPE_AGENT);
        while (__hip_atomic_load(c, __ATOMIC_ACQUIRE, __HIP_MEMORY_SCOPE_AGENT) < nblk)
            __builtin_amdgcn_s_sleep(8);
        __threadfence();
    }
    __syncthreads();
}

// ---- prologue mega-kernel: GCN + build_z + weight transpose/convert ----
// 128 blocks x 256 threads, 5 phases with grid barriers between dependent ones.
__global__ __launch_bounds__(256)
void prologue(const float* __restrict__ x, const int* __restrict__ ei,
              const float* __restrict__ gw, const float* __restrict__ gb,
              const float* __restrict__ W1, const float* __restrict__ W2,
              const float* __restrict__ W3,
              unsigned short* __restrict__ W1t, unsigned short* __restrict__ W2t,
              unsigned short* __restrict__ W3t,
              int* __restrict__ c1, float* __restrict__ S, float* __restrict__ dinv,
              unsigned short* __restrict__ z, int* __restrict__ ctr)
{
    const int nb = gridDim.x;            // 128
    const int bid = blockIdx.x, tid = threadIdx.x;
    const int gthr = nb * 256, gt = bid * 256 + tid;
    const int* dst = ei + EEDGES;

    // phase 0: zero c1, S
    for (int i = gt; i < NEQ_; i += gthr) { c1[i] = 0; S[i] = 0.f; }
    gridbar(ctr + 0, nb);

    // phase 1: degree histogram
    for (int e = gt; e < EEDGES; e += gthr) atomicAdd(&c1[dst[e]], 1);
    gridbar(ctr + 1, nb);

    // phase 2: dinv = rsqrt(512*count + 1)
    for (int i = gt; i < NEQ_; i += gthr) dinv[i] = rsqrtf(512.f * (float)c1[i] + 1.f);
    gridbar(ctr + 2, nb);

    // phase 3: scatter S[d] += dinv[s]*xf[s]
    for (int e = gt; e < EEDGES; e += gthr) {
        int s = ei[e], d = dst[e];
        float xf = x[(size_t)(s & 511) * XDIM_ + (s >> 9)];
        atomicAdd(&S[d], dinv[s] * xf);
    }
    gridbar(ctr + 3, nb);

    // phase 4a: build z[b][i] (bf16)
    {
        float w00 = gw[0], b0 = gb[0];
        for (int b = bid; b < 512; b += nb) {
            for (int i = tid; i < XDIM_; i += 256) {
                float xv = x[(size_t)b * XDIM_ + i];
                float v;
                if (i >= NEQ_) {
                    v = xv;
                } else if (i >= 8) {
                    v = fmaxf(w00 * xv + b0, 0.f);
                } else {
                    int n = i * 512 + b;
                    float deg = 512.f * (float)c1[n] + 1.f;
                    v = fmaxf(w00 * (512.f * dinv[n] * S[n] + xv / deg) + b0, 0.f);
                }
                z[(size_t)b * XDIM_ + i] = f2bf(v);
            }
        }
    }

    // phase 4b: tcvt all three weights, virtual-block grid-stride (r3-validated body)
    {
        const int lane = tid & 63, wave = tid >> 6;
        const int totvb = 6144 + 2048 + 4096;   // W1 + W2 + W3 virtual blocks
        for (int vb = bid; vb < totvb; vb += nb) {
            const float* W; unsigned short* Wt; int K, N, bx, by;
            if (vb < 6144)      { W = W1; Wt = W1t; K = 6144; N = 2048; bx = vb & 127;          by = vb >> 7; }
            else if (vb < 8192) { int l = vb - 6144; W = W2; Wt = W2t; K = 2048; N = 2048; bx = l & 127; by = l >> 7; }
            else                { int l = vb - 8192; W = W3; Wt = W3t; K = 2048; N = 4096; bx = l & 255; by = l >> 8; }
            int n  = bx * 16 + (lane >> 2);
            int kb = (by * 4 + wave) * 32 + (lane & 3) * 8;
            union { unsigned short h[8]; uint4 u; } cv;
            #pragma unroll
            for (int j = 0; j < 8; ++j) cv.h[j] = f2bf(W[(size_t)(kb + j) * N + n]);
            *(uint4*)(Wt + (size_t)n * K + kb) = cv.u;
        }
    }
}

// ---- 64x64-tile MFMA GEMM (r3-validated core), BK=64, 4 waves of 32x32 ----
// AMODE 0: A = bf16 [M][K], staged via global_load_lds.
// AMODE 1: A = relu(Pa[0]+Pa[1]+biasPrev) computed in-register during staging
//          (fuses previous layer's split-K reduce + bias + relu; Pa f32 [2][M][K]).
// OMODE 0: write f32 partial to Pout[blockIdx.z][M][N] (no bias).
// OMODE 1: write f32 Cout = acc + biasOut (final layer).
template<int AMODE, int OMODE>
__global__ __launch_bounds__(256)
void gemm_f(const unsigned short* __restrict__ A,
            const float* __restrict__ Pa, const float* __restrict__ biasPrev,
            const unsigned short* __restrict__ Bt,
            float* __restrict__ Pout,
            float* __restrict__ Cout, const float* __restrict__ biasOut,
            int M, int N, int K, int kChunk)
{
    __shared__ unsigned short As[2 * 64 * 32];   // 8 KB  [kh][row][32]
    __shared__ unsigned short Bs[2 * 64 * 32];   // 8 KB
    const int tid = threadIdx.x, lane = tid & 63, wave = tid >> 6;
    const int m0 = blockIdx.x * 64, n0 = blockIdx.y * 64;
    const int wm = (wave >> 1) * 32, wn = (wave & 1) * 32;
    const int fr = lane & 15, fko = (lane >> 4) * 8;
    const int k0 = blockIdx.z * kChunk, k1 = k0 + kChunk;

    const int srow = tid >> 2;
    const int sko  = (tid & 3) * 8;
    const size_t boff = (size_t)(n0 + srow) * K + sko;
    unsigned short* bsl0 = &Bs[srow * 32 + sko];
    unsigned short* bsl1 = &Bs[2048 + srow * 32 + sko];

    // AMODE 0 pointers
    const size_t aoff = (size_t)(m0 + srow) * K + sko;
    unsigned short* asl0 = &As[srow * 32 + sko];
    unsigned short* asl1 = &As[2048 + srow * 32 + sko];
    // AMODE 1 pointers
    const float* p0 = Pa + (size_t)(m0 + srow) * K + sko;
    const float* p1 = p0 + (size_t)M * K;

    f32x4 acc[2][2] = {};

    for (int kk = k0; kk < k1; kk += 64) {
        gll16(Bt + boff + kk,      bsl0);
        gll16(Bt + boff + kk + 32, bsl1);
        if (AMODE == 0) {
            gll16(A + aoff + kk,      asl0);
            gll16(A + aoff + kk + 32, asl1);
        } else {
            #pragma unroll
            for (int kh = 0; kh < 2; ++kh) {
                int off = kk + kh * 32;
                f32x4 q0 = *(const f32x4*)(p0 + off);
                f32x4 q1 = *(const f32x4*)(p0 + off + 4);
                f32x4 r0 = *(const f32x4*)(p1 + off);
                f32x4 r1 = *(const f32x4*)(p1 + off + 4);
                f32x4 c0 = *(const f32x4*)(biasPrev + off + sko);
                f32x4 c1v = *(const f32x4*)(biasPrev + off + sko + 4);
                q0 += r0 + c0;
                q1 += r1 + c1v;
                uint4 w;
                w.x = pk2(q0[0], q0[1]);
                w.y = pk2(q0[2], q0[3]);
                w.z = pk2(q1[0], q1[1]);
                w.w = pk2(q1[2], q1[3]);
                *(uint4*)(&As[kh * 2048 + srow * 32 + sko]) = w;
            }
        }
        __syncthreads();

        bf16x8 af[2][2], bf[2][2];
        #pragma unroll
        for (int kh = 0; kh < 2; ++kh)
            #pragma unroll
            for (int t = 0; t < 2; ++t) {
                af[t][kh] = *(const bf16x8*)(&As[kh * 2048 + (wm + t * 16 + fr) * 32 + fko]);
                bf[t][kh] = *(const bf16x8*)(&Bs[kh * 2048 + (wn + t * 16 + fr) * 32 + fko]);
            }
        #pragma unroll
        for (int kh = 0; kh < 2; ++kh)
            #pragma unroll
            for (int mt = 0; mt < 2; ++mt)
                #pragma unroll
                for (int nt = 0; nt < 2; ++nt)
                    acc[mt][nt] = __builtin_amdgcn_mfma_f32_16x16x32_bf16(
                        af[mt][kh], bf[nt][kh], acc[mt][nt], 0, 0, 0);

        __syncthreads();
    }

    const int col = lane & 15, qr = (lane >> 4) * 4;
    if (OMODE == 0) {
        float* Pp = Pout + (size_t)blockIdx.z * M * N;
        #pragma unroll
        for (int mt = 0; mt < 2; ++mt)
        #pragma unroll
        for (int nt = 0; nt < 2; ++nt) {
            int gm = m0 + wm + mt * 16 + qr;
            int gn = n0 + wn + nt * 16 + col;
            #pragma unroll
            for (int r = 0; r < 4; ++r)
                Pp[(size_t)(gm + r) * N + gn] = acc[mt][nt][r];
        }
    } else {
        #pragma unroll
        for (int mt = 0; mt < 2; ++mt)
        #pragma unroll
        for (int nt = 0; nt < 2; ++nt) {
            int gm = m0 + wm + mt * 16 + qr;
            int gn = n0 + wn + nt * 16 + col;
            float bv = biasOut[gn];
            #pragma unroll
            for (int r = 0; r < 4; ++r)
                Cout[(size_t)(gm + r) * N + gn] = acc[mt][nt][r] + bv;
        }
    }
}

extern "C" void kernel_launch(void* const* d_in, const int* in_sizes, int n_in,
                              void* d_out, int out_size, void* d_ws, size_t ws_size,
                              hipStream_t stream)
{
    const float* x  = (const float*)d_in[0];
    const int*   ei = (const int*)d_in[1];
    const float* gw = (const float*)d_in[2];
    const float* gb = (const float*)d_in[3];
    const float* W1 = (const float*)d_in[4];
    const float* b1 = (const float*)d_in[5];
    const float* W2 = (const float*)d_in[6];
    const float* b2 = (const float*)d_in[7];
    const float* W3 = (const float*)d_in[8];
    const float* b3 = (const float*)d_in[9];
    float* out = (float*)d_out;

    char* ws = (char*)d_ws;
    unsigned short* z   = (unsigned short*)(ws);               //  6,291,456 B
    unsigned short* W1t = (unsigned short*)(ws + 6291456);     // 25,165,824 B
    unsigned short* W2t = (unsigned short*)(ws + 31457280);    //  8,388,608 B
    unsigned short* W3t = (unsigned short*)(ws + 39845888);    // 16,777,216 B
    float* Pa           = (float*)        (ws + 56623104);     //  8,388,608 B  [2][512][2048] f32
    float* Pb           = (float*)        (ws + 65011712);     //  8,388,608 B
    int*   c1           = (int*)          (ws + 73400320);     // 16 KB
    float* Sg           = (float*)        (ws + 73416704);     // 16 KB
    float* dinv         = (float*)        (ws + 73433088);     // 16 KB
    int*   ctr          = (int*)          (ws + 73449472);     // 4 ints

    // zero the grid-barrier counters (capturable async memset)
    hipMemsetAsync(ctr, 0, 16, stream);

    // 1 launch: GCN + build_z + all weight transposes (grid-synced phases)
    hipLaunchKernelGGL(prologue, dim3(128), dim3(256), 0, stream,
                       x, ei, gw, gb, W1, W2, W3, W1t, W2t, W3t, c1, Sg, dinv, z, ctr);

    // L1: z[512,6144] @ W1t -> Pa (f32, S=2). grid 8x32x2 = 512 blocks, 48 iters
    hipLaunchKernelGGL((gemm_f<0, 0>), dim3(8, 32, 2), dim3(256), 0, stream,
                       z, nullptr, nullptr, W1t, Pa, nullptr, nullptr, 512, 2048, 6144, 3072);

    // L2: relu(Pa0+Pa1+b1) @ W2t -> Pb (f32, S=2). grid 8x32x2, 16 iters; reduce fused in A-staging
    hipLaunchKernelGGL((gemm_f<1, 0>), dim3(8, 32, 2), dim3(256), 0, stream,
                       nullptr, Pa, b1, W2t, Pb, nullptr, nullptr, 512, 2048, 2048, 1024);

    // L3: relu(Pb0+Pb1+b2) @ W3t + b3 -> out (f32). grid 8x64x1 = 512 blocks, 32 iters
    hipLaunchKernelGGL((gemm_f<1, 1>), dim3(8, 64, 1), dim3(256), 0, stream,
                       nullptr, Pb, b2, W3t, nullptr, out, b3, 512, 4096, 2048, 2048);
}